// Round 3
// baseline (1841.075 us; speedup 1.0000x reference)
//
#include <hip/hip_runtime.h>
#include <hip/hip_bf16.h>
#include <math.h>

#define NN 2048
#define TT 32
#define DD 256
#define HH 8
#define KK 32
#define EE 8192
#define ROWS (NN*TT)    // 65536
#define PS 160          // P row stride: [Aq|Bq|Ak|Bk|V] x 32 cols

typedef short s8v __attribute__((ext_vector_type(8)));
typedef float f4v __attribute__((ext_vector_type(4)));

__device__ __forceinline__ float bfu2f(unsigned short u){
  return __uint_as_float(((unsigned int)u)<<16);
}
__device__ __forceinline__ unsigned short f2bfu(float f){
  __hip_bfloat16 h = __float2bfloat16(f);
  return *reinterpret_cast<unsigned short*>(&h);
}
__device__ __forceinline__ void ld8bf(const unsigned short* p, float* o){
  uint4 u = *reinterpret_cast<const uint4*>(p);
  const unsigned short* us = reinterpret_cast<const unsigned short*>(&u);
#pragma unroll
  for(int i=0;i<8;i++) o[i] = bfu2f(us[i]);
}

// ---------------- CSR build ----------------
__global__ void k_zero_i32(int* p, int n){
  int i = blockIdx.x*256 + threadIdx.x;
  if(i<n) p[i]=0;
}
__global__ void k_hist(const int* __restrict__ recv, int* __restrict__ deg){
  int e = blockIdx.x*256 + threadIdx.x;
  if(e<EE) atomicAdd(&deg[recv[e]], 1);
}
__global__ void k_scan(const int* __restrict__ deg, int* __restrict__ offs, int* __restrict__ cursor){
  __shared__ int buf[2][NN];
  int tid = threadIdx.x;
  for(int i=tid;i<NN;i+=256) buf[0][i] = deg[i];
  __syncthreads();
  int src = 0;
  for(int off=1; off<NN; off<<=1){
    for(int i=tid;i<NN;i+=256){
      int v = buf[src][i];
      if(i>=off) v += buf[src][i-off];
      buf[1-src][i] = v;
    }
    src = 1-src;
    __syncthreads();
  }
  for(int i=tid;i<NN;i+=256){
    int ex = (i==0)?0:buf[src][i-1];
    offs[i]=ex; cursor[i]=ex;
  }
  if(tid==0) offs[NN]=EE;
}
__global__ void k_scatter(const int* __restrict__ recv, int* __restrict__ cursor, int* __restrict__ elist){
  int e = blockIdx.x*256 + threadIdx.x;
  if(e<EE){
    int pos = atomicAdd(&cursor[recv[e]], 1);
    elist[pos] = e;
  }
}

// ---------------- LayerNorm: fp32 in -> bf16 out ----------------
__global__ __launch_bounds__(256) void k_ln_f2b(const float* __restrict__ x,
    const float* __restrict__ sc, const float* __restrict__ of,
    unsigned short* __restrict__ out){
  int gw = (blockIdx.x*256 + threadIdx.x)>>6;
  int lane = threadIdx.x & 63;
  size_t base = (size_t)gw*DD + lane*4;
  float4 xv = *reinterpret_cast<const float4*>(x + base);
  float v[4] = {xv.x, xv.y, xv.z, xv.w};
  float s = v[0]+v[1]+v[2]+v[3];
  float q = v[0]*v[0]+v[1]*v[1]+v[2]*v[2]+v[3]*v[3];
#pragma unroll
  for(int o=32;o>0;o>>=1){ s += __shfl_xor(s,o); q += __shfl_xor(q,o); }
  float mean = s*(1.0f/DD);
  float var = q*(1.0f/DD) - mean*mean;
  float rs = rsqrtf(var + 1e-5f);
  float4 scv = *reinterpret_cast<const float4*>(sc + lane*4);
  float4 ofv = *reinterpret_cast<const float4*>(of + lane*4);
  ushort4 o4;
  o4.x = f2bfu((v[0]-mean)*rs*scv.x+ofv.x);
  o4.y = f2bfu((v[1]-mean)*rs*scv.y+ofv.y);
  o4.z = f2bfu((v[2]-mean)*rs*scv.z+ofv.z);
  o4.w = f2bfu((v[3]-mean)*rs*scv.w+ofv.w);
  *reinterpret_cast<ushort4*>(out + base) = o4;
}

// out = LN(nodes + attn_total), fp32 out   (attn buffer already includes D2)
__global__ __launch_bounds__(256) void k_final(
    const float* __restrict__ nodes, const float* __restrict__ attn,
    const float* __restrict__ sc, const float* __restrict__ of,
    float* __restrict__ out){
  int gw = (blockIdx.x*256 + threadIdx.x)>>6;
  int lane = threadIdx.x & 63;
  size_t base = (size_t)gw*DD + lane*4;
  float4 a4 = *reinterpret_cast<const float4*>(nodes + base);
  float4 c4 = *reinterpret_cast<const float4*>(attn + base);
  float v[4];
  v[0]=a4.x+c4.x; v[1]=a4.y+c4.y; v[2]=a4.z+c4.z; v[3]=a4.w+c4.w;
  float s = v[0]+v[1]+v[2]+v[3];
  float q = v[0]*v[0]+v[1]*v[1]+v[2]*v[2]+v[3]*v[3];
#pragma unroll
  for(int o=32;o>0;o>>=1){ s += __shfl_xor(s,o); q += __shfl_xor(q,o); }
  float mean = s*(1.0f/DD);
  float var = q*(1.0f/DD) - mean*mean;
  float rs = rsqrtf(var + 1e-5f);
  float4 scv = *reinterpret_cast<const float4*>(sc + lane*4);
  float4 ofv = *reinterpret_cast<const float4*>(of + lane*4);
  float4 o4;
  o4.x = (v[0]-mean)*rs*scv.x+ofv.x;
  o4.y = (v[1]-mean)*rs*scv.y+ofv.y;
  o4.z = (v[2]-mean)*rs*scv.z+ofv.z;
  o4.w = (v[3]-mean)*rs*scv.w+ofv.w;
  *reinterpret_cast<float4*>(out + base) = o4;
}

// ---------------- Weight transpose + fp32->bf16: in[R][C] f32 -> out[C][R] bf16 ----------------
__global__ void k_transpose(const float* __restrict__ in, unsigned short* __restrict__ out,
                            int R, int C){
  __shared__ unsigned short tile[32][33];
  int c0 = blockIdx.x*32, r0 = blockIdx.y*32;
  int tx = threadIdx.x & 31, ty = threadIdx.x >> 5;
  for(int i=ty;i<32;i+=8){
    int r = r0+i, c = c0+tx;
    tile[i][tx] = (r<R && c<C) ? f2bfu(in[(size_t)r*C + c]) : (unsigned short)0;
  }
  __syncthreads();
  for(int i=ty;i<32;i+=8){
    int c = c0+i, r = r0+tx;
    if(c<C && r<R) out[(size_t)c*R + r] = tile[tx][i];
  }
}

// ---------------- Per-pass projection GEMM: P[ROWS][160] for head h ----------------
// blockIdx.y = b in 0..4 selects {Aq,Bq,Ak,Bk,V} slice (32 output cols each).
__global__ __launch_bounds__(256) void k_proj(
    const unsigned short* __restrict__ A,       // nnorm [ROWS][256] bf16
    const unsigned short* __restrict__ wq0, const unsigned short* __restrict__ wq1,
    const unsigned short* __restrict__ wk0, const unsigned short* __restrict__ wk1,
    const unsigned short* __restrict__ wv,
    const float* __restrict__ bq, const float* __restrict__ bk,
    const float* __restrict__ bv,
    unsigned short* __restrict__ P, int h){
  __shared__ unsigned short Asm[256*32];
  __shared__ unsigned short Bsm[32*32];
  int tid = threadIdx.x, lane = tid&63, wid = tid>>6;
  int b = blockIdx.y;
  const unsigned short* Bt;
  const float* bias = nullptr;
  if(b==0){ Bt=wq0; bias=bq; }
  else if(b==1){ Bt=wq1; }
  else if(b==2){ Bt=wk0; bias=bk; }
  else if(b==3){ Bt=wk1; }
  else { Bt=wv; bias=bv; }
  Bt += (size_t)h*32*256;
  if(bias) bias += h*32;
  int m0 = blockIdx.x*256;
  f4v acc[4][2];
#pragma unroll
  for(int mi=0;mi<4;mi++)
#pragma unroll
    for(int ni=0;ni<2;ni++) acc[mi][ni] = (f4v){0.f,0.f,0.f,0.f};
  int q = lane>>4, l16 = lane&15;
  for(int k0=0;k0<256;k0+=32){
#pragma unroll
    for(int j=0;j<4;j++){
      int idx = tid + 256*j;
      int row = idx>>2, col = (idx&3)*8;
      *reinterpret_cast<float4*>(&Asm[row*32+col]) =
        *reinterpret_cast<const float4*>(A + (size_t)(m0+row)*256 + k0 + col);
    }
    if(tid<128){
      int row = tid>>2, col = (tid&3)*8;
      *reinterpret_cast<float4*>(&Bsm[row*32+col]) =
        *reinterpret_cast<const float4*>(Bt + (size_t)row*256 + k0 + col);
    }
    __syncthreads();
    s8v af[4], bfr[2];
#pragma unroll
    for(int mi=0;mi<4;mi++) af[mi]  = *reinterpret_cast<const s8v*>(&Asm[(wid*64+mi*16+l16)*32 + q*8]);
#pragma unroll
    for(int ni=0;ni<2;ni++) bfr[ni] = *reinterpret_cast<const s8v*>(&Bsm[(ni*16+l16)*32 + q*8]);
#pragma unroll
    for(int mi=0;mi<4;mi++)
#pragma unroll
      for(int ni=0;ni<2;ni++)
        acc[mi][ni] = __builtin_amdgcn_mfma_f32_16x16x32_bf16(af[mi], bfr[ni], acc[mi][ni], 0, 0, 0);
    __syncthreads();
  }
#pragma unroll
  for(int mi=0;mi<4;mi++)
#pragma unroll
    for(int ni=0;ni<2;ni++){
      int col = ni*16 + l16;
      float bvv = bias ? bias[col] : 0.f;
#pragma unroll
      for(int r=0;r<4;r++){
        int crow = m0 + wid*64 + mi*16 + q*4 + r;
        P[(size_t)crow*PS + b*32 + col] = f2bfu(acc[mi][ni][r] + bvv);
      }
    }
}

// ---------------- Attention: logits for head h ----------------
__global__ __launch_bounds__(256) void k_logits(
    const unsigned short* __restrict__ P,
    const float* __restrict__ alibi,
    const int* __restrict__ senders, const int* __restrict__ receivers,
    float* __restrict__ S, int h){
  __shared__ float Qs[4][TT][TT+1];
  __shared__ float Ks[4][TT][TT+1];
  int wid = threadIdx.x>>6, lane = threadIdx.x&63;
  int e = blockIdx.x*4 + wid;
  int sn = senders[e], rn = receivers[e];
  int t = lane>>1, kh = (lane&1)*16;
  size_t rs = ((size_t)sn*TT + t)*PS;
  size_t rr = ((size_t)rn*TT + t)*PS;
  float a0[8], a1[8], b0[8], b1[8];
  // Q = Aq[s] + Bq[r]   (bq baked into Aq)
  ld8bf(P+rs+0+kh,  a0); ld8bf(P+rs+0+kh+8,  a1);
  ld8bf(P+rr+32+kh, b0); ld8bf(P+rr+32+kh+8, b1);
#pragma unroll
  for(int i=0;i<8;i++){ Qs[wid][t][kh+i] = a0[i]+b0[i]; Qs[wid][t][kh+8+i] = a1[i]+b1[i]; }
  // K = Ak[s] + Bk[r]   (bk baked into Ak)
  ld8bf(P+rs+64+kh, a0); ld8bf(P+rs+64+kh+8, a1);
  ld8bf(P+rr+96+kh, b0); ld8bf(P+rr+96+kh+8, b1);
#pragma unroll
  for(int i=0;i<8;i++){ Ks[wid][t][kh+i] = a0[i]+b0[i]; Ks[wid][t][kh+8+i] = a1[i]+b1[i]; }
  __syncthreads();
  int Tp = lane&31, tb = (lane>>5)*16;
  const float rsK = 0.17677669529663687f;   // 1/sqrt(32)
  float* Sb = S + (size_t)e*(TT*TT);
#pragma unroll
  for(int ti=0;ti<16;ti++){
    int tt = tb+ti;
    float sum = 0.f;
#pragma unroll
    for(int k=0;k<KK;k++) sum += Qs[wid][tt][k]*Ks[wid][Tp][k];
    float al = alibi[(h*TT+tt)*TT + Tp];
    float val = (Tp<=tt) ? (al + sum*rsK) : -1e30f;
    Sb[tt*TT + Tp] = val;
  }
}

// ---------------- Attention: online segment softmax + apply V (head h) ----------------
__global__ __launch_bounds__(256) void k_apply(
    const float* __restrict__ S, const unsigned short* __restrict__ P,
    const int* __restrict__ offs, const int* __restrict__ elist,
    const int* __restrict__ senders,
    float* __restrict__ attn, int h){
  __shared__ float Ws[4][TT][TT+1];
  __shared__ float Vs[4][TT][TT+1];
  __shared__ int degs[4];
  int wid = threadIdx.x>>6, lane = threadIdx.x&63;
  int n = blockIdx.x*4 + wid;
  int o0 = offs[n];
  int deg = offs[n+1]-o0;
  if(lane==0) degs[wid]=deg;
  __syncthreads();
  int bmax = max(max(degs[0],degs[1]),max(degs[2],degs[3]));
  int Tp = lane&31, tb = (lane>>5)*16;
  float M[16], Dn[16], acc16[16];
#pragma unroll
  for(int i=0;i<16;i++){ M[i]=-3.0e38f; Dn[i]=0.f; acc16[i]=0.f; }
  // online max+denom sweep
  for(int ei=0;ei<deg;ei++){
    const float* Sb = S + (size_t)elist[o0+ei]*(TT*TT);
#pragma unroll
    for(int ti=0;ti<16;ti++){
      float v = Sb[(tb+ti)*TT + Tp];
      float mn = fmaxf(M[ti], v);
      Dn[ti] = Dn[ti]*__expf(M[ti]-mn) + __expf(v-mn);
      M[ti] = mn;
    }
  }
  int d = lane&31;
  int tv = lane>>1, dh = (lane&1)*16;
  for(int ei=0;ei<bmax;ei++){
    bool active = ei<deg;
    if(active){
      int e = elist[o0+ei];
      const float* Sb = S + (size_t)e*(TT*TT);
#pragma unroll
      for(int ti=0;ti<16;ti++)
        Ws[wid][tb+ti][Tp] = __expf(Sb[(tb+ti)*TT + Tp] - M[ti]) / Dn[ti];
      int sv = senders[e];
      const unsigned short* vp = P + ((size_t)sv*TT + tv)*PS + 128 + dh;
      float f0[8], f1[8]; ld8bf(vp, f0); ld8bf(vp+8, f1);
#pragma unroll
      for(int i=0;i<8;i++){ Vs[wid][tv][dh+i]=f0[i]; Vs[wid][tv][dh+8+i]=f1[i]; }
    }
    __syncthreads();
    if(active){
#pragma unroll
      for(int ti=0;ti<16;ti++){
        float a = 0.f;
#pragma unroll
        for(int Tq=0;Tq<TT;Tq++) a += Ws[wid][tb+ti][Tq]*Vs[wid][Tq][d];
        acc16[ti] += a;
      }
    }
    __syncthreads();
  }
  float* op = attn + ((size_t)n*TT + tb)*DD + h*KK + d;
#pragma unroll
  for(int ti=0;ti<16;ti++) op[ti*DD] = acc16[ti];
}

// ---------------- FFN GEMM (128x128 tiles): out = [gelu](A@Bt^T + bias) ----------------
// If Cacc != null: Cacc[crow*256+ccol] += v  (fp32 accumulate), else Cbf stores bf16.
__global__ __launch_bounds__(256) void k_gemm128(
    const unsigned short* __restrict__ A, int lda,
    const unsigned short* __restrict__ Bt, int ldb,
    unsigned short* __restrict__ Cbf, float* __restrict__ Cacc,
    int K, const float* __restrict__ bias, int act){
  __shared__ unsigned short Asm[128*32];
  __shared__ unsigned short Bsm[128*32];
  int tid = threadIdx.x;
  int lane = tid & 63, wid = tid >> 6;
  int wrow = (wid>>1)*64, wcol = (wid&1)*64;
  int m0 = blockIdx.x*128, n0 = blockIdx.y*128;
  f4v acc[4][4];
#pragma unroll
  for(int mi=0;mi<4;mi++)
#pragma unroll
    for(int ni=0;ni<4;ni++) acc[mi][ni] = (f4v){0.f,0.f,0.f,0.f};
  int q = lane>>4, l16 = lane&15;
  for(int k0=0;k0<K;k0+=32){
#pragma unroll
    for(int j=0;j<2;j++){
      int c = tid + 256*j;
      int row = c>>2, col = (c&3)*8;
      *reinterpret_cast<float4*>(&Asm[row*32+col]) =
        *reinterpret_cast<const float4*>(A + (size_t)(m0+row)*lda + k0 + col);
      *reinterpret_cast<float4*>(&Bsm[row*32+col]) =
        *reinterpret_cast<const float4*>(Bt + (size_t)(n0+row)*ldb + k0 + col);
    }
    __syncthreads();
    s8v af[4], bfr[4];
#pragma unroll
    for(int mi=0;mi<4;mi++) af[mi]  = *reinterpret_cast<const s8v*>(&Asm[(wrow+mi*16+l16)*32 + q*8]);
#pragma unroll
    for(int ni=0;ni<4;ni++) bfr[ni] = *reinterpret_cast<const s8v*>(&Bsm[(wcol+ni*16+l16)*32 + q*8]);
#pragma unroll
    for(int mi=0;mi<4;mi++)
#pragma unroll
      for(int ni=0;ni<4;ni++)
        acc[mi][ni] = __builtin_amdgcn_mfma_f32_16x16x32_bf16(af[mi], bfr[ni], acc[mi][ni], 0, 0, 0);
    __syncthreads();
  }
#pragma unroll
  for(int mi=0;mi<4;mi++)
#pragma unroll
    for(int ni=0;ni<4;ni++){
      int ccol = n0 + wcol + ni*16 + l16;
      float bv = bias ? bias[ccol] : 0.f;
#pragma unroll
      for(int r=0;r<4;r++){
        int crow = m0 + wrow + mi*16 + q*4 + r;
        float v = acc[mi][ni][r] + bv;
        if(act==1){
          float x = v;
          v = 0.5f*x*(1.f + tanhf(0.7978845608028654f*(x + 0.044715f*x*x*x)));
        }
        if(Cacc) Cacc[(size_t)crow*256 + ccol] += v;
        else     Cbf[(size_t)crow*256 + ccol] = f2bfu(v);
      }
    }
}

// ---------------- Orchestration ----------------
extern "C" void kernel_launch(void* const* d_in, const int* in_sizes, int n_in,
                              void* d_out, int out_size, void* d_ws, size_t ws_size,
                              hipStream_t stream) {
  const float* nodes    = (const float*)d_in[0];
  const int*   senders  = (const int*)d_in[1];
  const int*   receivers= (const int*)d_in[2];
  const float* alibi    = (const float*)d_in[3];
  const float* lnq_s    = (const float*)d_in[4];
  const float* lnq_o    = (const float*)d_in[5];
  const float* Wq       = (const float*)d_in[6];
  const float* bq       = (const float*)d_in[7];
  const float* Wk       = (const float*)d_in[8];
  const float* bk       = (const float*)d_in[9];
  const float* Wv       = (const float*)d_in[10];
  const float* bv       = (const float*)d_in[11];
  const float* lnm_s    = (const float*)d_in[12];
  const float* lnm_o    = (const float*)d_in[13];
  const float* W1       = (const float*)d_in[14];
  const float* b1       = (const float*)d_in[15];
  const float* W2       = (const float*)d_in[16];
  const float* b2       = (const float*)d_in[17];
  const float* lno_s    = (const float*)d_in[18];
  const float* lno_o    = (const float*)d_in[19];

  char* ws = (char*)d_ws;
  // layout (total ~157 MiB, proven safe in round 2):
  size_t o_nnorm = 0;                         // bf16 ROWS*256 = 33,554,432 ; H1c overlay later
  size_t o_P     = 33554432;                  // bf16 ROWS*160 = 20,971,520 ; Xm overlay later (spans into S)
  size_t o_S     = 54525952;                  // fp32 EE*1024  = 33,554,432
  size_t o_attn  = 88080384;                  // fp32 ROWS*256 = 67,108,864 (gets D2 accumulated)
  size_t o_w     = 155189248;
  size_t o_wqt0  = o_w + 0;
  size_t o_wqt1  = o_w + 131072;
  size_t o_wkt0  = o_w + 262144;
  size_t o_wkt1  = o_w + 393216;
  size_t o_wvt   = o_w + 524288;
  size_t o_w1t   = o_w + 655360;              // 1024x256 bf16
  size_t o_w2t   = o_w + 1179648;             // 256x1024 bf16
  size_t o_csr   = o_w + 1703936;
  size_t o_deg   = o_csr;
  size_t o_offs  = o_csr + 8192;
  size_t o_cur   = o_csr + 16640;
  size_t o_elist = o_csr + 24832;             // ends ~156,950,784

  unsigned short* nnorm = (unsigned short*)(ws + o_nnorm);
  unsigned short* P     = (unsigned short*)(ws + o_P);
  float* Sbuf = (float*)(ws + o_S);
  float* attn = (float*)(ws + o_attn);
  unsigned short* wqt0 = (unsigned short*)(ws + o_wqt0);
  unsigned short* wqt1 = (unsigned short*)(ws + o_wqt1);
  unsigned short* wkt0 = (unsigned short*)(ws + o_wkt0);
  unsigned short* wkt1 = (unsigned short*)(ws + o_wkt1);
  unsigned short* wvt  = (unsigned short*)(ws + o_wvt);
  unsigned short* w1t  = (unsigned short*)(ws + o_w1t);
  unsigned short* w2t  = (unsigned short*)(ws + o_w2t);
  int* deg    = (int*)(ws + o_deg);
  int* offs   = (int*)(ws + o_offs);
  int* cursor = (int*)(ws + o_cur);
  int* elist  = (int*)(ws + o_elist);
  unsigned short* Xm  = (unsigned short*)(ws + o_P);      // overlay (P+S dead after attention)
  unsigned short* H1c = (unsigned short*)(ws + o_nnorm);  // overlay (nnorm dead after last proj)

  // CSR build
  k_zero_i32<<<8, 256, 0, stream>>>(deg, NN);
  k_hist<<<EE/256, 256, 0, stream>>>(receivers, deg);
  k_scan<<<1, 256, 0, stream>>>(deg, offs, cursor);
  k_scatter<<<EE/256, 256, 0, stream>>>(receivers, cursor, elist);

  // LN(nodes) -> nnorm (bf16)
  k_ln_f2b<<<ROWS/4, 256, 0, stream>>>(nodes, lnq_s, lnq_o, nnorm);

  // transpose weights (fp32 -> bf16) to [outcol][k]
  k_transpose<<<dim3(8,8),  256, 0, stream>>>(Wq,           wqt0, 256, 256);
  k_transpose<<<dim3(8,8),  256, 0, stream>>>(Wq + 256*256, wqt1, 256, 256);
  k_transpose<<<dim3(8,8),  256, 0, stream>>>(Wk,           wkt0, 256, 256);
  k_transpose<<<dim3(8,8),  256, 0, stream>>>(Wk + 256*256, wkt1, 256, 256);
  k_transpose<<<dim3(8,8),  256, 0, stream>>>(Wv,           wvt,  256, 256);
  k_transpose<<<dim3(32,8), 256, 0, stream>>>(W1,           w1t,  256, 1024);
  k_transpose<<<dim3(8,32), 256, 0, stream>>>(W2,           w2t,  1024, 256);

  // attention: 8 single-head passes
  for(int h=0;h<HH;h++){
    k_proj  <<<dim3(ROWS/256, 5), 256, 0, stream>>>(nnorm, wqt0, wqt1, wkt0, wkt1, wvt, bq, bk, bv, P, h);
    k_logits<<<EE/4, 256, 0, stream>>>(P, alibi, senders, receivers, Sbuf, h);
    k_apply <<<NN/4, 256, 0, stream>>>(Sbuf, P, offs, elist, senders, attn, h);
  }

  // FFN (4 chunks of 256 hidden cols), D2 accumulated into attn
  k_ln_f2b<<<ROWS/4, 256, 0, stream>>>(attn, lnm_s, lnm_o, Xm);
  for(int c=0;c<4;c++){
    k_gemm128<<<dim3(ROWS/128, 2), 256, 0, stream>>>(Xm, 256, w1t + (size_t)c*256*256, 256,
                                                     H1c, nullptr, 256, b1 + c*256, 1);
    k_gemm128<<<dim3(ROWS/128, 2), 256, 0, stream>>>(H1c, 256, w2t + (size_t)c*256, 1024,
                                                     nullptr, attn, 256, (c==0)? b2 : nullptr, 0);
  }

  // out = LN(nodes + attn)
  k_final<<<ROWS/4, 256, 0, stream>>>(nodes, attn, lno_s, lno_o, (float*)d_out);
}

// Round 4
// 1054.186 us; speedup vs baseline: 1.7464x; 1.7464x over previous
//
#include <hip/hip_runtime.h>
#include <hip/hip_bf16.h>
#include <math.h>

#define NN 2048
#define TT 32
#define DD 256
#define HH 8
#define KK 32
#define EE 8192
#define ROWS (NN*TT)    // 65536
#define HS 2            // heads per pass
#define PS2 320         // P row stride: [Aq|Bq|Ak|Bk|V] x (HS*32) cols

typedef short s8v __attribute__((ext_vector_type(8)));
typedef float f4v __attribute__((ext_vector_type(4)));

__device__ __forceinline__ float bfu2f(unsigned short u){
  return __uint_as_float(((unsigned int)u)<<16);
}
__device__ __forceinline__ unsigned short f2bfu(float f){
  __hip_bfloat16 h = __float2bfloat16(f);
  return *reinterpret_cast<unsigned short*>(&h);
}
__device__ __forceinline__ void ld8bf(const unsigned short* p, float* o){
  uint4 u = *reinterpret_cast<const uint4*>(p);
  const unsigned short* us = reinterpret_cast<const unsigned short*>(&u);
#pragma unroll
  for(int i=0;i<8;i++) o[i] = bfu2f(us[i]);
}

// ---------------- CSR build ----------------
__global__ void k_zero_i32(int* p, int n){
  int i = blockIdx.x*256 + threadIdx.x;
  if(i<n) p[i]=0;
}
__global__ void k_hist(const int* __restrict__ recv, int* __restrict__ deg){
  int e = blockIdx.x*256 + threadIdx.x;
  if(e<EE) atomicAdd(&deg[recv[e]], 1);
}
__global__ void k_scan(const int* __restrict__ deg, int* __restrict__ offs, int* __restrict__ cursor){
  __shared__ int buf[2][NN];
  int tid = threadIdx.x;
  for(int i=tid;i<NN;i+=256) buf[0][i] = deg[i];
  __syncthreads();
  int src = 0;
  for(int off=1; off<NN; off<<=1){
    for(int i=tid;i<NN;i+=256){
      int v = buf[src][i];
      if(i>=off) v += buf[src][i-off];
      buf[1-src][i] = v;
    }
    src = 1-src;
    __syncthreads();
  }
  for(int i=tid;i<NN;i+=256){
    int ex = (i==0)?0:buf[src][i-1];
    offs[i]=ex; cursor[i]=ex;
  }
  if(tid==0) offs[NN]=EE;
}
__global__ void k_scatter(const int* __restrict__ recv, int* __restrict__ cursor, int* __restrict__ elist){
  int e = blockIdx.x*256 + threadIdx.x;
  if(e<EE){
    int pos = atomicAdd(&cursor[recv[e]], 1);
    elist[pos] = e;
  }
}

// ---------------- LayerNorm: fp32 in -> bf16 out ----------------
__global__ __launch_bounds__(256) void k_ln_f2b(const float* __restrict__ x,
    const float* __restrict__ sc, const float* __restrict__ of,
    unsigned short* __restrict__ out){
  int gw = (blockIdx.x*256 + threadIdx.x)>>6;
  int lane = threadIdx.x & 63;
  size_t base = (size_t)gw*DD + lane*4;
  float4 xv = *reinterpret_cast<const float4*>(x + base);
  float v[4] = {xv.x, xv.y, xv.z, xv.w};
  float s = v[0]+v[1]+v[2]+v[3];
  float q = v[0]*v[0]+v[1]*v[1]+v[2]*v[2]+v[3]*v[3];
#pragma unroll
  for(int o=32;o>0;o>>=1){ s += __shfl_xor(s,o); q += __shfl_xor(q,o); }
  float mean = s*(1.0f/DD);
  float var = q*(1.0f/DD) - mean*mean;
  float rs = rsqrtf(var + 1e-5f);
  float4 scv = *reinterpret_cast<const float4*>(sc + lane*4);
  float4 ofv = *reinterpret_cast<const float4*>(of + lane*4);
  ushort4 o4;
  o4.x = f2bfu((v[0]-mean)*rs*scv.x+ofv.x);
  o4.y = f2bfu((v[1]-mean)*rs*scv.y+ofv.y);
  o4.z = f2bfu((v[2]-mean)*rs*scv.z+ofv.z);
  o4.w = f2bfu((v[3]-mean)*rs*scv.w+ofv.w);
  *reinterpret_cast<ushort4*>(out + base) = o4;
}

// out = LN(nodes + attn_total), fp32 out   (attn buffer already includes D2)
__global__ __launch_bounds__(256) void k_final(
    const float* __restrict__ nodes, const float* __restrict__ attn,
    const float* __restrict__ sc, const float* __restrict__ of,
    float* __restrict__ out){
  int gw = (blockIdx.x*256 + threadIdx.x)>>6;
  int lane = threadIdx.x & 63;
  size_t base = (size_t)gw*DD + lane*4;
  float4 a4 = *reinterpret_cast<const float4*>(nodes + base);
  float4 c4 = *reinterpret_cast<const float4*>(attn + base);
  float v[4];
  v[0]=a4.x+c4.x; v[1]=a4.y+c4.y; v[2]=a4.z+c4.z; v[3]=a4.w+c4.w;
  float s = v[0]+v[1]+v[2]+v[3];
  float q = v[0]*v[0]+v[1]*v[1]+v[2]*v[2]+v[3]*v[3];
#pragma unroll
  for(int o=32;o>0;o>>=1){ s += __shfl_xor(s,o); q += __shfl_xor(q,o); }
  float mean = s*(1.0f/DD);
  float var = q*(1.0f/DD) - mean*mean;
  float rs = rsqrtf(var + 1e-5f);
  float4 scv = *reinterpret_cast<const float4*>(sc + lane*4);
  float4 ofv = *reinterpret_cast<const float4*>(of + lane*4);
  float4 o4;
  o4.x = (v[0]-mean)*rs*scv.x+ofv.x;
  o4.y = (v[1]-mean)*rs*scv.y+ofv.y;
  o4.z = (v[2]-mean)*rs*scv.z+ofv.z;
  o4.w = (v[3]-mean)*rs*scv.w+ofv.w;
  *reinterpret_cast<float4*>(out + base) = o4;
}

// ---------------- Weight transpose + fp32->bf16: in[R][C] f32 -> out[C][R] bf16 ----------------
__global__ void k_transpose(const float* __restrict__ in, unsigned short* __restrict__ out,
                            int R, int C){
  __shared__ unsigned short tile[32][33];
  int c0 = blockIdx.x*32, r0 = blockIdx.y*32;
  int tx = threadIdx.x & 31, ty = threadIdx.x >> 5;
  for(int i=ty;i<32;i+=8){
    int r = r0+i, c = c0+tx;
    tile[i][tx] = (r<R && c<C) ? f2bfu(in[(size_t)r*C + c]) : (unsigned short)0;
  }
  __syncthreads();
  for(int i=ty;i<32;i+=8){
    int c = c0+i, r = r0+tx;
    if(c<C && r<R) out[(size_t)c*R + r] = tile[tx][i];
  }
}

// ---------------- Per-pass projection GEMM: P[ROWS][320] for heads h0,h0+1 ----------------
// blockIdx.y = 0..9: group g = y>>1 in {Aq,Bq,Ak,Bk,V}, head hh = y&1.
__global__ __launch_bounds__(256) void k_proj(
    const unsigned short* __restrict__ A,       // nnorm [ROWS][256] bf16
    const unsigned short* __restrict__ wq0, const unsigned short* __restrict__ wq1,
    const unsigned short* __restrict__ wk0, const unsigned short* __restrict__ wk1,
    const unsigned short* __restrict__ wv,
    const float* __restrict__ bq, const float* __restrict__ bk,
    const float* __restrict__ bv,
    unsigned short* __restrict__ P, int h0){
  __shared__ unsigned short Asm[256*32];
  __shared__ unsigned short Bsm[32*32];
  int tid = threadIdx.x, lane = tid&63, wid = tid>>6;
  int b = blockIdx.y;
  int g = b>>1, hh = b&1, hcur = h0+hh;
  const unsigned short* Bt;
  const float* bias = nullptr;
  if(g==0){ Bt=wq0; bias=bq; }
  else if(g==1){ Bt=wq1; }
  else if(g==2){ Bt=wk0; bias=bk; }
  else if(g==3){ Bt=wk1; }
  else { Bt=wv; bias=bv; }
  Bt += (size_t)hcur*32*256;
  if(bias) bias += hcur*32;
  int cbase = g*64 + hh*32;
  int m0 = blockIdx.x*256;
  f4v acc[4][2];
#pragma unroll
  for(int mi=0;mi<4;mi++)
#pragma unroll
    for(int ni=0;ni<2;ni++) acc[mi][ni] = (f4v){0.f,0.f,0.f,0.f};
  int q = lane>>4, l16 = lane&15;
  for(int k0=0;k0<256;k0+=32){
#pragma unroll
    for(int j=0;j<4;j++){
      int idx = tid + 256*j;
      int row = idx>>2, col = (idx&3)*8;
      *reinterpret_cast<float4*>(&Asm[row*32+col]) =
        *reinterpret_cast<const float4*>(A + (size_t)(m0+row)*256 + k0 + col);
    }
    if(tid<128){
      int row = tid>>2, col = (tid&3)*8;
      *reinterpret_cast<float4*>(&Bsm[row*32+col]) =
        *reinterpret_cast<const float4*>(Bt + (size_t)row*256 + k0 + col);
    }
    __syncthreads();
    s8v af[4], bfr[2];
#pragma unroll
    for(int mi=0;mi<4;mi++) af[mi]  = *reinterpret_cast<const s8v*>(&Asm[(wid*64+mi*16+l16)*32 + q*8]);
#pragma unroll
    for(int ni=0;ni<2;ni++) bfr[ni] = *reinterpret_cast<const s8v*>(&Bsm[(ni*16+l16)*32 + q*8]);
#pragma unroll
    for(int mi=0;mi<4;mi++)
#pragma unroll
      for(int ni=0;ni<2;ni++)
        acc[mi][ni] = __builtin_amdgcn_mfma_f32_16x16x32_bf16(af[mi], bfr[ni], acc[mi][ni], 0, 0, 0);
    __syncthreads();
  }
#pragma unroll
  for(int mi=0;mi<4;mi++)
#pragma unroll
    for(int ni=0;ni<2;ni++){
      int col = ni*16 + l16;
      float bvv = bias ? bias[col] : 0.f;
#pragma unroll
      for(int r=0;r<4;r++){
        int crow = m0 + wid*64 + mi*16 + q*4 + r;
        P[(size_t)crow*PS2 + cbase + col] = f2bfu(acc[mi][ni][r] + bvv);
      }
    }
}

// ---------------- Fused attention: one wave per (node, head) ----------------
// Element-wise (over edges) segment softmax; MFMA for QK^T and P@V.
__device__ __forceinline__ void stage_qk(const unsigned short* __restrict__ P, size_t rowS,
    const float* BqR, const float* BkR,
    unsigned short* QsW, unsigned short* KsW, int t2, int half){
  float x[8], y[8];
  const unsigned short* aq = P + rowS;          // Aq slice
  ld8bf(aq, x); ld8bf(aq+8, y);
  s8v qa, qb;
#pragma unroll
  for(int j=0;j<8;j++){ qa[j] = (short)f2bfu(x[j]+BqR[j]); qb[j] = (short)f2bfu(y[j]+BqR[8+j]); }
  int lb = t2*40 + half*16;
  *reinterpret_cast<s8v*>(&QsW[lb])   = qa;
  *reinterpret_cast<s8v*>(&QsW[lb+8]) = qb;
  const unsigned short* ak = P + rowS + 128;    // Ak slice
  ld8bf(ak, x); ld8bf(ak+8, y);
  s8v ka, kb;
#pragma unroll
  for(int j=0;j<8;j++){ ka[j] = (short)f2bfu(x[j]+BkR[j]); kb[j] = (short)f2bfu(y[j]+BkR[8+j]); }
  *reinterpret_cast<s8v*>(&KsW[lb])   = ka;
  *reinterpret_cast<s8v*>(&KsW[lb+8]) = kb;
}

__global__ __launch_bounds__(256) void k_attn(
    const unsigned short* __restrict__ P,
    const float* __restrict__ alibi,
    const int* __restrict__ offs, const int* __restrict__ elist,
    const int* __restrict__ senders,
    float* __restrict__ attn, int h0){
  __shared__ unsigned short Qs[4][32*40];   // Q tile; later reused for P tile
  __shared__ unsigned short Ks[4][32*40];   // K tile; later reused for V^T tile
  int wid = threadIdx.x>>6, lane = threadIdx.x&63;
  int g = blockIdx.x*4 + wid;
  int n = g>>1, hh = g&1, h = h0+hh;
  int q = lane>>4, l16 = lane&15;
  int t2 = lane>>1, half = lane&1;
  unsigned short* QsW = Qs[wid];
  unsigned short* KsW = Ks[wid];
  const float rsK = 0.17677669529663687f;   // 1/sqrt(32)

  // per-node Bq/Bk slices (receiver side), bf16->fp32 regs
  size_t rowN = ((size_t)n*TT + t2)*PS2 + hh*32 + half*16;
  float BqR[16], BkR[16];
  ld8bf(P + rowN + 64,  BqR); ld8bf(P + rowN + 64 + 8,  BqR+8);
  ld8bf(P + rowN + 192, BkR); ld8bf(P + rowN + 192 + 8, BkR+8);

  // alibi for my 16 C-layout elements
  float AlR[2][2][4];
#pragma unroll
  for(int mt=0;mt<2;mt++)
#pragma unroll
    for(int nt=0;nt<2;nt++)
#pragma unroll
      for(int r=0;r<4;r++)
        AlR[mt][nt][r] = alibi[(size_t)h*TT*TT + (mt*16+q*4+r)*TT + nt*16+l16];

  int o0 = offs[n], deg = offs[n+1]-o0;
  f4v M[2][2], D[2][2], O[2][2];
#pragma unroll
  for(int mt=0;mt<2;mt++)
#pragma unroll
    for(int nt=0;nt<2;nt++){
      M[mt][nt] = (f4v){-3.0e38f,-3.0e38f,-3.0e38f,-3.0e38f};
      D[mt][nt] = (f4v){0.f,0.f,0.f,0.f};
      O[mt][nt] = (f4v){0.f,0.f,0.f,0.f};
    }
  f4v zero = (f4v){0.f,0.f,0.f,0.f};

  // ---- sweep 1: element-wise running max + denom over edges ----
  for(int ei=0; ei<deg; ei++){
    int e = elist[o0+ei];
    int s = senders[e];
    size_t rowS = ((size_t)s*TT + t2)*PS2 + hh*32 + half*16;
    stage_qk(P, rowS, BqR, BkR, QsW, KsW, t2, half);
    s8v aq0 = *reinterpret_cast<const s8v*>(&QsW[(l16)*40 + q*8]);
    s8v aq1 = *reinterpret_cast<const s8v*>(&QsW[(16+l16)*40 + q*8]);
    s8v bk0 = *reinterpret_cast<const s8v*>(&KsW[(l16)*40 + q*8]);
    s8v bk1 = *reinterpret_cast<const s8v*>(&KsW[(16+l16)*40 + q*8]);
    f4v S[2][2];
    S[0][0] = __builtin_amdgcn_mfma_f32_16x16x32_bf16(aq0, bk0, zero, 0,0,0);
    S[0][1] = __builtin_amdgcn_mfma_f32_16x16x32_bf16(aq0, bk1, zero, 0,0,0);
    S[1][0] = __builtin_amdgcn_mfma_f32_16x16x32_bf16(aq1, bk0, zero, 0,0,0);
    S[1][1] = __builtin_amdgcn_mfma_f32_16x16x32_bf16(aq1, bk1, zero, 0,0,0);
#pragma unroll
    for(int mt=0;mt<2;mt++)
#pragma unroll
      for(int nt=0;nt<2;nt++)
#pragma unroll
        for(int r=0;r<4;r++){
          int row = mt*16+q*4+r, col = nt*16+l16;
          float v = (col<=row) ? (AlR[mt][nt][r] + S[mt][nt][r]*rsK) : -1e30f;
          float mo = M[mt][nt][r];
          float mn = fmaxf(mo, v);
          D[mt][nt][r] = D[mt][nt][r]*__expf(mo-mn) + __expf(v-mn);
          M[mt][nt][r] = mn;
        }
  }
  // invert denominators
#pragma unroll
  for(int mt=0;mt<2;mt++)
#pragma unroll
    for(int nt=0;nt<2;nt++)
#pragma unroll
      for(int r=0;r<4;r++)
        D[mt][nt][r] = 1.0f / D[mt][nt][r];

  // ---- sweep 2: recompute S, exact weights, P@V accumulate ----
  for(int ei=0; ei<deg; ei++){
    int e = elist[o0+ei];
    int s = senders[e];
    size_t rowS = ((size_t)s*TT + t2)*PS2 + hh*32 + half*16;
    stage_qk(P, rowS, BqR, BkR, QsW, KsW, t2, half);
    s8v aq0 = *reinterpret_cast<const s8v*>(&QsW[(l16)*40 + q*8]);
    s8v aq1 = *reinterpret_cast<const s8v*>(&QsW[(16+l16)*40 + q*8]);
    s8v bk0 = *reinterpret_cast<const s8v*>(&KsW[(l16)*40 + q*8]);
    s8v bk1 = *reinterpret_cast<const s8v*>(&KsW[(16+l16)*40 + q*8]);
    f4v S[2][2];
    S[0][0] = __builtin_amdgcn_mfma_f32_16x16x32_bf16(aq0, bk0, zero, 0,0,0);
    S[0][1] = __builtin_amdgcn_mfma_f32_16x16x32_bf16(aq0, bk1, zero, 0,0,0);
    S[1][0] = __builtin_amdgcn_mfma_f32_16x16x32_bf16(aq1, bk0, zero, 0,0,0);
    S[1][1] = __builtin_amdgcn_mfma_f32_16x16x32_bf16(aq1, bk1, zero, 0,0,0);
    // write weights (bf16) into QsW as the P-operand tile [t][T']
#pragma unroll
    for(int mt=0;mt<2;mt++)
#pragma unroll
      for(int nt=0;nt<2;nt++)
#pragma unroll
        for(int r=0;r<4;r++){
          int row = mt*16+q*4+r, col = nt*16+l16;
          float v = (col<=row) ? (AlR[mt][nt][r] + S[mt][nt][r]*rsK) : -1e30f;
          float w = __expf(v - M[mt][nt][r]) * D[mt][nt][r];
          QsW[row*40 + col] = f2bfu(w);
        }
    // stage V transposed into KsW: Vt[d][T']
    {
      const unsigned short* vp = P + ((size_t)s*TT + t2)*PS2 + 256 + hh*32 + half*16;
      float va[8], vb[8]; ld8bf(vp, va); ld8bf(vp+8, vb);
#pragma unroll
      for(int j=0;j<8;j++){
        KsW[(half*16+j)*40 + t2]   = f2bfu(va[j]);
        KsW[(half*16+8+j)*40 + t2] = f2bfu(vb[j]);
      }
    }
    s8v ap0 = *reinterpret_cast<const s8v*>(&QsW[(l16)*40 + q*8]);
    s8v ap1 = *reinterpret_cast<const s8v*>(&QsW[(16+l16)*40 + q*8]);
    s8v bv0 = *reinterpret_cast<const s8v*>(&KsW[(l16)*40 + q*8]);
    s8v bv1 = *reinterpret_cast<const s8v*>(&KsW[(16+l16)*40 + q*8]);
    O[0][0] = __builtin_amdgcn_mfma_f32_16x16x32_bf16(ap0, bv0, O[0][0], 0,0,0);
    O[0][1] = __builtin_amdgcn_mfma_f32_16x16x32_bf16(ap0, bv1, O[0][1], 0,0,0);
    O[1][0] = __builtin_amdgcn_mfma_f32_16x16x32_bf16(ap1, bv0, O[1][0], 0,0,0);
    O[1][1] = __builtin_amdgcn_mfma_f32_16x16x32_bf16(ap1, bv1, O[1][1], 0,0,0);
  }

  // write messages (deg==0 -> zeros, matches segment_sum)
#pragma unroll
  for(int mt=0;mt<2;mt++)
#pragma unroll
    for(int dt=0;dt<2;dt++)
#pragma unroll
      for(int r=0;r<4;r++){
        int row = mt*16+q*4+r;
        attn[((size_t)n*TT + row)*DD + h*KK + dt*16 + l16] = O[mt][dt][r];
      }
}

// ---------------- FFN GEMM (128x128 tiles): out = [gelu](A@Bt^T + bias) ----------------
__global__ __launch_bounds__(256) void k_gemm128(
    const unsigned short* __restrict__ A, int lda,
    const unsigned short* __restrict__ Bt, int ldb,
    unsigned short* __restrict__ Cbf, float* __restrict__ Cacc,
    int K, const float* __restrict__ bias, int act){
  __shared__ unsigned short Asm[128*32];
  __shared__ unsigned short Bsm[128*32];
  int tid = threadIdx.x;
  int lane = tid & 63, wid = tid >> 6;
  int wrow = (wid>>1)*64, wcol = (wid&1)*64;
  int m0 = blockIdx.x*128, n0 = blockIdx.y*128;
  f4v acc[4][4];
#pragma unroll
  for(int mi=0;mi<4;mi++)
#pragma unroll
    for(int ni=0;ni<4;ni++) acc[mi][ni] = (f4v){0.f,0.f,0.f,0.f};
  int q = lane>>4, l16 = lane&15;
  for(int k0=0;k0<K;k0+=32){
#pragma unroll
    for(int j=0;j<2;j++){
      int c = tid + 256*j;
      int row = c>>2, col = (c&3)*8;
      *reinterpret_cast<float4*>(&Asm[row*32+col]) =
        *reinterpret_cast<const float4*>(A + (size_t)(m0+row)*lda + k0 + col);
      *reinterpret_cast<float4*>(&Bsm[row*32+col]) =
        *reinterpret_cast<const float4*>(Bt + (size_t)(n0+row)*ldb + k0 + col);
    }
    __syncthreads();
    s8v af[4], bfr[4];
#pragma unroll
    for(int mi=0;mi<4;mi++) af[mi]  = *reinterpret_cast<const s8v*>(&Asm[(wrow+mi*16+l16)*32 + q*8]);
#pragma unroll
    for(int ni=0;ni<4;ni++) bfr[ni] = *reinterpret_cast<const s8v*>(&Bsm[(wcol+ni*16+l16)*32 + q*8]);
#pragma unroll
    for(int mi=0;mi<4;mi++)
#pragma unroll
      for(int ni=0;ni<4;ni++)
        acc[mi][ni] = __builtin_amdgcn_mfma_f32_16x16x32_bf16(af[mi], bfr[ni], acc[mi][ni], 0, 0, 0);
    __syncthreads();
  }
#pragma unroll
  for(int mi=0;mi<4;mi++)
#pragma unroll
    for(int ni=0;ni<4;ni++){
      int ccol = n0 + wcol + ni*16 + l16;
      float bv = bias ? bias[ccol] : 0.f;
#pragma unroll
      for(int r=0;r<4;r++){
        int crow = m0 + wrow + mi*16 + q*4 + r;
        float v = acc[mi][ni][r] + bv;
        if(act==1){
          float x = v;
          v = 0.5f*x*(1.f + tanhf(0.7978845608028654f*(x + 0.044715f*x*x*x)));
        }
        if(Cacc) Cacc[(size_t)crow*256 + ccol] += v;
        else     Cbf[(size_t)crow*256 + ccol] = f2bfu(v);
      }
    }
}

// ---------------- Orchestration ----------------
extern "C" void kernel_launch(void* const* d_in, const int* in_sizes, int n_in,
                              void* d_out, int out_size, void* d_ws, size_t ws_size,
                              hipStream_t stream) {
  const float* nodes    = (const float*)d_in[0];
  const int*   senders  = (const int*)d_in[1];
  const int*   receivers= (const int*)d_in[2];
  const float* alibi    = (const float*)d_in[3];
  const float* lnq_s    = (const float*)d_in[4];
  const float* lnq_o    = (const float*)d_in[5];
  const float* Wq       = (const float*)d_in[6];
  const float* bq       = (const float*)d_in[7];
  const float* Wk       = (const float*)d_in[8];
  const float* bk       = (const float*)d_in[9];
  const float* Wv       = (const float*)d_in[10];
  const float* bv       = (const float*)d_in[11];
  const float* lnm_s    = (const float*)d_in[12];
  const float* lnm_o    = (const float*)d_in[13];
  const float* W1       = (const float*)d_in[14];
  const float* b1       = (const float*)d_in[15];
  const float* W2       = (const float*)d_in[16];
  const float* b2       = (const float*)d_in[17];
  const float* lno_s    = (const float*)d_in[18];
  const float* lno_o    = (const float*)d_in[19];

  char* ws = (char*)d_ws;
  // layout (total ~144.4 MiB; 157 MiB proven safe in rounds 2-3):
  size_t o_nnorm = 0;                         // bf16 ROWS*256 = 33,554,432 ; H1c overlay later
  size_t o_P2    = 33554432;                  // bf16 ROWS*320 = 41,943,040 ; Xm overlay later
  size_t o_attn  = 75497472;                  // fp32 ROWS*256 = 67,108,864 (gets D2 accumulated)
  size_t o_w     = 142606336;
  size_t o_wqt0  = o_w + 0;
  size_t o_wqt1  = o_w + 131072;
  size_t o_wkt0  = o_w + 262144;
  size_t o_wkt1  = o_w + 393216;
  size_t o_wvt   = o_w + 524288;
  size_t o_w1t   = o_w + 655360;              // 1024x256 bf16
  size_t o_w2t   = o_w + 1179648;             // 256x1024 bf16
  size_t o_csr   = o_w + 1703936;
  size_t o_deg   = o_csr;
  size_t o_offs  = o_csr + 8192;
  size_t o_cur   = o_csr + 16640;
  size_t o_elist = o_csr + 24832;             // ends ~144.4 MB

  unsigned short* nnorm = (unsigned short*)(ws + o_nnorm);
  unsigned short* P2    = (unsigned short*)(ws + o_P2);
  float* attn = (float*)(ws + o_attn);
  unsigned short* wqt0 = (unsigned short*)(ws + o_wqt0);
  unsigned short* wqt1 = (unsigned short*)(ws + o_wqt1);
  unsigned short* wkt0 = (unsigned short*)(ws + o_wkt0);
  unsigned short* wkt1 = (unsigned short*)(ws + o_wkt1);
  unsigned short* wvt  = (unsigned short*)(ws + o_wvt);
  unsigned short* w1t  = (unsigned short*)(ws + o_w1t);
  unsigned short* w2t  = (unsigned short*)(ws + o_w2t);
  int* deg    = (int*)(ws + o_deg);
  int* offs   = (int*)(ws + o_offs);
  int* cursor = (int*)(ws + o_cur);
  int* elist  = (int*)(ws + o_elist);
  unsigned short* Xm  = (unsigned short*)(ws + o_P2);     // overlay (P2 dead after attention)
  unsigned short* H1c = (unsigned short*)(ws + o_nnorm);  // overlay (nnorm dead after last proj)

  // CSR build
  k_zero_i32<<<8, 256, 0, stream>>>(deg, NN);
  k_hist<<<EE/256, 256, 0, stream>>>(receivers, deg);
  k_scan<<<1, 256, 0, stream>>>(deg, offs, cursor);
  k_scatter<<<EE/256, 256, 0, stream>>>(receivers, cursor, elist);

  // LN(nodes) -> nnorm (bf16)
  k_ln_f2b<<<ROWS/4, 256, 0, stream>>>(nodes, lnq_s, lnq_o, nnorm);

  // transpose weights (fp32 -> bf16) to [outcol][k]
  k_transpose<<<dim3(8,8),  256, 0, stream>>>(Wq,           wqt0, 256, 256);
  k_transpose<<<dim3(8,8),  256, 0, stream>>>(Wq + 256*256, wqt1, 256, 256);
  k_transpose<<<dim3(8,8),  256, 0, stream>>>(Wk,           wkt0, 256, 256);
  k_transpose<<<dim3(8,8),  256, 0, stream>>>(Wk + 256*256, wkt1, 256, 256);
  k_transpose<<<dim3(8,8),  256, 0, stream>>>(Wv,           wvt,  256, 256);
  k_transpose<<<dim3(32,8), 256, 0, stream>>>(W1,           w1t,  256, 1024);
  k_transpose<<<dim3(8,32), 256, 0, stream>>>(W2,           w2t,  1024, 256);

  // attention: 4 passes of 2 heads
  for(int p=0;p<HH/HS;p++){
    int h0 = p*HS;
    k_proj<<<dim3(ROWS/256, 10), 256, 0, stream>>>(nnorm, wqt0, wqt1, wkt0, wkt1, wvt, bq, bk, bv, P2, h0);
    k_attn<<<NN*HS/4, 256, 0, stream>>>(P2, alibi, offs, elist, senders, attn, h0);
  }

  // FFN (4 chunks of 256 hidden cols), D2 accumulated into attn
  k_ln_f2b<<<ROWS/4, 256, 0, stream>>>(attn, lnm_s, lnm_o, Xm);
  for(int c=0;c<4;c++){
    k_gemm128<<<dim3(ROWS/128, 2), 256, 0, stream>>>(Xm, 256, w1t + (size_t)c*256*256, 256,
                                                     H1c, nullptr, 256, b1 + c*256, 1);
    k_gemm128<<<dim3(ROWS/128, 2), 256, 0, stream>>>(H1c, 256, w2t + (size_t)c*256, 1024,
                                                     nullptr, attn, 256, (c==0)? b2 : nullptr, 0);
  }

  // out = LN(nodes + attn)
  k_final<<<ROWS/4, 256, 0, stream>>>(nodes, attn, lno_s, lno_o, (float*)d_out);
}

// Round 5
// 912.068 us; speedup vs baseline: 2.0186x; 1.1558x over previous
//
#include <hip/hip_runtime.h>
#include <hip/hip_bf16.h>
#include <math.h>

#define NN 2048
#define TT 32
#define DD 256
#define HH 8
#define KK 32
#define EE 8192
#define ROWS (NN*TT)    // 65536
#define HS 2            // heads per pass
#define PS2 320         // P row stride: [Aq|Bq|Ak|Bk|V] x (HS*32) cols

typedef short s8v __attribute__((ext_vector_type(8)));
typedef float f4v __attribute__((ext_vector_type(4)));

typedef __attribute__((address_space(3))) unsigned char lds_t;
typedef __attribute__((address_space(1))) const unsigned char glob_t;
__device__ __forceinline__ void glds16(const void* g, void* l){
  __builtin_amdgcn_global_load_lds((glob_t*)g, (lds_t*)l, 16, 0, 0);
}

__device__ __forceinline__ float bfu2f(unsigned short u){
  return __uint_as_float(((unsigned int)u)<<16);
}
__device__ __forceinline__ unsigned short f2bfu(float f){
  __hip_bfloat16 h = __float2bfloat16(f);
  return *reinterpret_cast<unsigned short*>(&h);
}
__device__ __forceinline__ void ld8bf(const unsigned short* p, float* o){
  uint4 u = *reinterpret_cast<const uint4*>(p);
  const unsigned short* us = reinterpret_cast<const unsigned short*>(&u);
#pragma unroll
  for(int i=0;i<8;i++) o[i] = bfu2f(us[i]);
}

// ---------------- CSR build ----------------
__global__ void k_zero_i32(int* p, int n){
  int i = blockIdx.x*256 + threadIdx.x;
  if(i<n) p[i]=0;
}
__global__ void k_hist(const int* __restrict__ recv, int* __restrict__ deg){
  int e = blockIdx.x*256 + threadIdx.x;
  if(e<EE) atomicAdd(&deg[recv[e]], 1);
}
__global__ void k_scan(const int* __restrict__ deg, int* __restrict__ offs, int* __restrict__ cursor){
  __shared__ int buf[2][NN];
  int tid = threadIdx.x;
  for(int i=tid;i<NN;i+=256) buf[0][i] = deg[i];
  __syncthreads();
  int src = 0;
  for(int off=1; off<NN; off<<=1){
    for(int i=tid;i<NN;i+=256){
      int v = buf[src][i];
      if(i>=off) v += buf[src][i-off];
      buf[1-src][i] = v;
    }
    src = 1-src;
    __syncthreads();
  }
  for(int i=tid;i<NN;i+=256){
    int ex = (i==0)?0:buf[src][i-1];
    offs[i]=ex; cursor[i]=ex;
  }
  if(tid==0) offs[NN]=EE;
}
__global__ void k_scatter(const int* __restrict__ recv, int* __restrict__ cursor, int* __restrict__ elist){
  int e = blockIdx.x*256 + threadIdx.x;
  if(e<EE){
    int pos = atomicAdd(&cursor[recv[e]], 1);
    elist[pos] = e;
  }
}

// ---------------- LayerNorm: fp32 in -> bf16 out ----------------
__global__ __launch_bounds__(256) void k_ln_f2b(const float* __restrict__ x,
    const float* __restrict__ sc, const float* __restrict__ of,
    unsigned short* __restrict__ out){
  int gw = (blockIdx.x*256 + threadIdx.x)>>6;
  int lane = threadIdx.x & 63;
  size_t base = (size_t)gw*DD + lane*4;
  float4 xv = *reinterpret_cast<const float4*>(x + base);
  float v[4] = {xv.x, xv.y, xv.z, xv.w};
  float s = v[0]+v[1]+v[2]+v[3];
  float q = v[0]*v[0]+v[1]*v[1]+v[2]*v[2]+v[3]*v[3];
#pragma unroll
  for(int o=32;o>0;o>>=1){ s += __shfl_xor(s,o); q += __shfl_xor(q,o); }
  float mean = s*(1.0f/DD);
  float var = q*(1.0f/DD) - mean*mean;
  float rs = rsqrtf(var + 1e-5f);
  float4 scv = *reinterpret_cast<const float4*>(sc + lane*4);
  float4 ofv = *reinterpret_cast<const float4*>(of + lane*4);
  ushort4 o4;
  o4.x = f2bfu((v[0]-mean)*rs*scv.x+ofv.x);
  o4.y = f2bfu((v[1]-mean)*rs*scv.y+ofv.y);
  o4.z = f2bfu((v[2]-mean)*rs*scv.z+ofv.z);
  o4.w = f2bfu((v[3]-mean)*rs*scv.w+ofv.w);
  *reinterpret_cast<ushort4*>(out + base) = o4;
}

// out = LN(nodes + attn_total), fp32 out   (attn buffer already includes D2)
__global__ __launch_bounds__(256) void k_final(
    const float* __restrict__ nodes, const float* __restrict__ attn,
    const float* __restrict__ sc, const float* __restrict__ of,
    float* __restrict__ out){
  int gw = (blockIdx.x*256 + threadIdx.x)>>6;
  int lane = threadIdx.x & 63;
  size_t base = (size_t)gw*DD + lane*4;
  float4 a4 = *reinterpret_cast<const float4*>(nodes + base);
  float4 c4 = *reinterpret_cast<const float4*>(attn + base);
  float v[4];
  v[0]=a4.x+c4.x; v[1]=a4.y+c4.y; v[2]=a4.z+c4.z; v[3]=a4.w+c4.w;
  float s = v[0]+v[1]+v[2]+v[3];
  float q = v[0]*v[0]+v[1]*v[1]+v[2]*v[2]+v[3]*v[3];
#pragma unroll
  for(int o=32;o>0;o>>=1){ s += __shfl_xor(s,o); q += __shfl_xor(q,o); }
  float mean = s*(1.0f/DD);
  float var = q*(1.0f/DD) - mean*mean;
  float rs = rsqrtf(var + 1e-5f);
  float4 scv = *reinterpret_cast<const float4*>(sc + lane*4);
  float4 ofv = *reinterpret_cast<const float4*>(of + lane*4);
  float4 o4;
  o4.x = (v[0]-mean)*rs*scv.x+ofv.x;
  o4.y = (v[1]-mean)*rs*scv.y+ofv.y;
  o4.z = (v[2]-mean)*rs*scv.z+ofv.z;
  o4.w = (v[3]-mean)*rs*scv.w+ofv.w;
  *reinterpret_cast<float4*>(out + base) = o4;
}

// ---------------- Weight transpose + fp32->bf16: in[R][C] f32 -> out[C][R] bf16 ----------------
__global__ void k_transpose(const float* __restrict__ in, unsigned short* __restrict__ out,
                            int R, int C){
  __shared__ unsigned short tile[32][33];
  int c0 = blockIdx.x*32, r0 = blockIdx.y*32;
  int tx = threadIdx.x & 31, ty = threadIdx.x >> 5;
  for(int i=ty;i<32;i+=8){
    int r = r0+i, c = c0+tx;
    tile[i][tx] = (r<R && c<C) ? f2bfu(in[(size_t)r*C + c]) : (unsigned short)0;
  }
  __syncthreads();
  for(int i=ty;i<32;i+=8){
    int c = c0+i, r = r0+tx;
    if(c<C && r<R) out[(size_t)c*R + r] = tile[tx][i];
  }
}

// ---------------- Build fused per-pass projection weights ----------------
// WTall[p][c][k] (bf16), c in [0,320): g=c>>6 in {Aq,Bq,Ak,Bk,V}, hh=(c>>5)&1, j=c&31
// biasall[p][c]: bq for g==0, bk for g==2, bv for g==4, else 0.
__global__ void k_buildw(const float* __restrict__ Wq, const float* __restrict__ Wk,
                         const float* __restrict__ Wv,
                         const float* __restrict__ bq, const float* __restrict__ bk,
                         const float* __restrict__ bv,
                         unsigned short* __restrict__ WTall, float* __restrict__ biasall){
  int bx = blockIdx.x;            // p*320 + c
  int p = bx/320, c = bx - p*320;
  int k = threadIdx.x;
  int g = c>>6, hh = (c>>5)&1, j = c&31;
  int h = p*HS + hh;
  int col = h*32 + j;
  float w;
  if(g==0)      w = Wq[(size_t)k*256 + col];
  else if(g==1) w = Wq[(size_t)(256+k)*256 + col];
  else if(g==2) w = Wk[(size_t)k*256 + col];
  else if(g==3) w = Wk[(size_t)(256+k)*256 + col];
  else          w = Wv[(size_t)k*256 + col];
  WTall[((size_t)bx)*256 + k] = f2bfu(w);
  if(k==0){
    float b = 0.f;
    if(g==0) b = bq[col];
    else if(g==2) b = bk[col];
    else if(g==4) b = bv[col];
    biasall[bx] = b;
  }
}

// ---------------- Projection GEMM: P2[ROWS][320] = nnorm @ WTall_p^T + bias ----------------
// 128x64 tiles, async global->LDS staging. grid (ROWS/128, 5).
__global__ __launch_bounds__(256) void k_projg(
    const unsigned short* __restrict__ A,      // [ROWS][256]
    const unsigned short* __restrict__ Bt,     // [320][256] for this pass
    const float* __restrict__ bias,            // [320]
    unsigned short* __restrict__ P){
  __shared__ unsigned short Asm[128*32];
  __shared__ unsigned short Bsm[64*32];
  int tid = threadIdx.x, lane = tid&63;
  int wid = tid>>6;
  int wrow = (wid>>1)*64, wcol = (wid&1)*32;
  int m0 = blockIdx.x*128, n0 = blockIdx.y*64;
  f4v acc[4][2];
#pragma unroll
  for(int mi=0;mi<4;mi++)
#pragma unroll
    for(int ni=0;ni<2;ni++) acc[mi][ni] = (f4v){0.f,0.f,0.f,0.f};
  int q = lane>>4, l16 = lane&15;
  int ra0 = tid>>2, ca0 = (tid&3)*8;
  int c1 = tid+256, ra1 = c1>>2, ca1 = (c1&3)*8;
  for(int k0=0;k0<256;k0+=32){
    glds16(A + (size_t)(m0+ra0)*256 + k0 + ca0, &Asm[tid*8]);
    glds16(A + (size_t)(m0+ra1)*256 + k0 + ca1, &Asm[c1*8]);
    glds16(Bt + (size_t)(n0+ra0)*256 + k0 + ca0, &Bsm[tid*8]);
    __syncthreads();
    s8v af[4], bfr[2];
#pragma unroll
    for(int mi=0;mi<4;mi++) af[mi]  = *reinterpret_cast<const s8v*>(&Asm[(wrow+mi*16+l16)*32 + q*8]);
#pragma unroll
    for(int ni=0;ni<2;ni++) bfr[ni] = *reinterpret_cast<const s8v*>(&Bsm[(wcol+ni*16+l16)*32 + q*8]);
#pragma unroll
    for(int mi=0;mi<4;mi++)
#pragma unroll
      for(int ni=0;ni<2;ni++)
        acc[mi][ni] = __builtin_amdgcn_mfma_f32_16x16x32_bf16(af[mi], bfr[ni], acc[mi][ni], 0, 0, 0);
    __syncthreads();
  }
#pragma unroll
  for(int mi=0;mi<4;mi++)
#pragma unroll
    for(int ni=0;ni<2;ni++){
      int ccol = n0 + wcol + ni*16 + l16;
      float bvv = bias[ccol];
#pragma unroll
      for(int r=0;r<4;r++){
        int crow = m0 + wrow + mi*16 + q*4 + r;
        P[(size_t)crow*PS2 + ccol] = f2bfu(acc[mi][ni][r] + bvv);
      }
    }
}

// ---------------- Fused attention: one wave per (node, head) ----------------
__device__ __forceinline__ void stage_qk(const unsigned short* __restrict__ P, size_t rowS,
    const float* BqR, const float* BkR,
    unsigned short* QsW, unsigned short* KsW, int t2, int half){
  float x[8], y[8];
  const unsigned short* aq = P + rowS;          // Aq slice
  ld8bf(aq, x); ld8bf(aq+8, y);
  s8v qa, qb;
#pragma unroll
  for(int j=0;j<8;j++){ qa[j] = (short)f2bfu(x[j]+BqR[j]); qb[j] = (short)f2bfu(y[j]+BqR[8+j]); }
  int lb = t2*40 + half*16;
  *reinterpret_cast<s8v*>(&QsW[lb])   = qa;
  *reinterpret_cast<s8v*>(&QsW[lb+8]) = qb;
  const unsigned short* ak = P + rowS + 128;    // Ak slice
  ld8bf(ak, x); ld8bf(ak+8, y);
  s8v ka, kb;
#pragma unroll
  for(int j=0;j<8;j++){ ka[j] = (short)f2bfu(x[j]+BkR[j]); kb[j] = (short)f2bfu(y[j]+BkR[8+j]); }
  *reinterpret_cast<s8v*>(&KsW[lb])   = ka;
  *reinterpret_cast<s8v*>(&KsW[lb+8]) = kb;
}

__global__ __launch_bounds__(256) void k_attn(
    const unsigned short* __restrict__ P,
    const float* __restrict__ alibi,
    const int* __restrict__ offs, const int* __restrict__ elist,
    const int* __restrict__ senders,
    float* __restrict__ attn, int h0){
  __shared__ unsigned short Qs[4][32*40];   // Q tile; later reused for P tile
  __shared__ unsigned short Ks[4][32*40];   // K tile; later reused for V^T tile
  int wid = threadIdx.x>>6, lane = threadIdx.x&63;
  int g = blockIdx.x*4 + wid;
  int n = g>>1, hh = g&1, h = h0+hh;
  int q = lane>>4, l16 = lane&15;
  int t2 = lane>>1, half = lane&1;
  unsigned short* QsW = Qs[wid];
  unsigned short* KsW = Ks[wid];
  const float rsK = 0.17677669529663687f;   // 1/sqrt(32)

  size_t rowN = ((size_t)n*TT + t2)*PS2 + hh*32 + half*16;
  float BqR[16], BkR[16];
  ld8bf(P + rowN + 64,  BqR); ld8bf(P + rowN + 64 + 8,  BqR+8);
  ld8bf(P + rowN + 192, BkR); ld8bf(P + rowN + 192 + 8, BkR+8);

  float AlR[2][2][4];
#pragma unroll
  for(int mt=0;mt<2;mt++)
#pragma unroll
    for(int nt=0;nt<2;nt++)
#pragma unroll
      for(int r=0;r<4;r++)
        AlR[mt][nt][r] = alibi[(size_t)h*TT*TT + (mt*16+q*4+r)*TT + nt*16+l16];

  int o0 = offs[n], deg = offs[n+1]-o0;
  f4v M[2][2], D[2][2], O[2][2];
#pragma unroll
  for(int mt=0;mt<2;mt++)
#pragma unroll
    for(int nt=0;nt<2;nt++){
      M[mt][nt] = (f4v){-3.0e38f,-3.0e38f,-3.0e38f,-3.0e38f};
      D[mt][nt] = (f4v){0.f,0.f,0.f,0.f};
      O[mt][nt] = (f4v){0.f,0.f,0.f,0.f};
    }
  f4v zero = (f4v){0.f,0.f,0.f,0.f};

  // ---- sweep 1: element-wise running max + denom over edges ----
  for(int ei=0; ei<deg; ei++){
    int e = elist[o0+ei];
    int s = senders[e];
    size_t rowS = ((size_t)s*TT + t2)*PS2 + hh*32 + half*16;
    stage_qk(P, rowS, BqR, BkR, QsW, KsW, t2, half);
    s8v aq0 = *reinterpret_cast<const s8v*>(&QsW[(l16)*40 + q*8]);
    s8v aq1 = *reinterpret_cast<const s8v*>(&QsW[(16+l16)*40 + q*8]);
    s8v bk0 = *reinterpret_cast<const s8v*>(&KsW[(l16)*40 + q*8]);
    s8v bk1 = *reinterpret_cast<const s8v*>(&KsW[(16+l16)*40 + q*8]);
    f4v S[2][2];
    S[0][0] = __builtin_amdgcn_mfma_f32_16x16x32_bf16(aq0, bk0, zero, 0,0,0);
    S[0][1] = __builtin_amdgcn_mfma_f32_16x16x32_bf16(aq0, bk1, zero, 0,0,0);
    S[1][0] = __builtin_amdgcn_mfma_f32_16x16x32_bf16(aq1, bk0, zero, 0,0,0);
    S[1][1] = __builtin_amdgcn_mfma_f32_16x16x32_bf16(aq1, bk1, zero, 0,0,0);
#pragma unroll
    for(int mt=0;mt<2;mt++)
#pragma unroll
      for(int nt=0;nt<2;nt++)
#pragma unroll
        for(int r=0;r<4;r++){
          int row = mt*16+q*4+r, col = nt*16+l16;
          float v = (col<=row) ? (AlR[mt][nt][r] + S[mt][nt][r]*rsK) : -1e30f;
          float mo = M[mt][nt][r];
          float mn = fmaxf(mo, v);
          D[mt][nt][r] = D[mt][nt][r]*__expf(mo-mn) + __expf(v-mn);
          M[mt][nt][r] = mn;
        }
  }
#pragma unroll
  for(int mt=0;mt<2;mt++)
#pragma unroll
    for(int nt=0;nt<2;nt++)
#pragma unroll
      for(int r=0;r<4;r++)
        D[mt][nt][r] = 1.0f / D[mt][nt][r];

  // ---- sweep 2: recompute S, exact weights, P@V accumulate ----
  for(int ei=0; ei<deg; ei++){
    int e = elist[o0+ei];
    int s = senders[e];
    size_t rowS = ((size_t)s*TT + t2)*PS2 + hh*32 + half*16;
    stage_qk(P, rowS, BqR, BkR, QsW, KsW, t2, half);
    s8v aq0 = *reinterpret_cast<const s8v*>(&QsW[(l16)*40 + q*8]);
    s8v aq1 = *reinterpret_cast<const s8v*>(&QsW[(16+l16)*40 + q*8]);
    s8v bk0 = *reinterpret_cast<const s8v*>(&KsW[(l16)*40 + q*8]);
    s8v bk1 = *reinterpret_cast<const s8v*>(&KsW[(16+l16)*40 + q*8]);
    f4v S[2][2];
    S[0][0] = __builtin_amdgcn_mfma_f32_16x16x32_bf16(aq0, bk0, zero, 0,0,0);
    S[0][1] = __builtin_amdgcn_mfma_f32_16x16x32_bf16(aq0, bk1, zero, 0,0,0);
    S[1][0] = __builtin_amdgcn_mfma_f32_16x16x32_bf16(aq1, bk0, zero, 0,0,0);
    S[1][1] = __builtin_amdgcn_mfma_f32_16x16x32_bf16(aq1, bk1, zero, 0,0,0);
#pragma unroll
    for(int mt=0;mt<2;mt++)
#pragma unroll
      for(int nt=0;nt<2;nt++)
#pragma unroll
        for(int r=0;r<4;r++){
          int row = mt*16+q*4+r, col = nt*16+l16;
          float v = (col<=row) ? (AlR[mt][nt][r] + S[mt][nt][r]*rsK) : -1e30f;
          float w = __expf(v - M[mt][nt][r]) * D[mt][nt][r];
          QsW[row*40 + col] = f2bfu(w);
        }
    {
      const unsigned short* vp = P + ((size_t)s*TT + t2)*PS2 + 256 + hh*32 + half*16;
      float va[8], vb[8]; ld8bf(vp, va); ld8bf(vp+8, vb);
#pragma unroll
      for(int j=0;j<8;j++){
        KsW[(half*16+j)*40 + t2]   = f2bfu(va[j]);
        KsW[(half*16+8+j)*40 + t2] = f2bfu(vb[j]);
      }
    }
    s8v ap0 = *reinterpret_cast<const s8v*>(&QsW[(l16)*40 + q*8]);
    s8v ap1 = *reinterpret_cast<const s8v*>(&QsW[(16+l16)*40 + q*8]);
    s8v bv0 = *reinterpret_cast<const s8v*>(&KsW[(l16)*40 + q*8]);
    s8v bv1 = *reinterpret_cast<const s8v*>(&KsW[(16+l16)*40 + q*8]);
    O[0][0] = __builtin_amdgcn_mfma_f32_16x16x32_bf16(ap0, bv0, O[0][0], 0,0,0);
    O[0][1] = __builtin_amdgcn_mfma_f32_16x16x32_bf16(ap0, bv1, O[0][1], 0,0,0);
    O[1][0] = __builtin_amdgcn_mfma_f32_16x16x32_bf16(ap1, bv0, O[1][0], 0,0,0);
    O[1][1] = __builtin_amdgcn_mfma_f32_16x16x32_bf16(ap1, bv1, O[1][1], 0,0,0);
  }

#pragma unroll
  for(int mt=0;mt<2;mt++)
#pragma unroll
    for(int dt=0;dt<2;dt++)
#pragma unroll
      for(int r=0;r<4;r++){
        int row = mt*16+q*4+r;
        attn[((size_t)n*TT + row)*DD + h*KK + dt*16 + l16] = O[mt][dt][r];
      }
}

// ---------------- FFN GEMM (128x128 tiles, async staging) ----------------
// Cbf (ldc, bf16) when Cacc==null, else Cacc[crow*ldc+ccol] += v.
__global__ __launch_bounds__(256) void k_gemmL(
    const unsigned short* __restrict__ A, int lda,
    const unsigned short* __restrict__ Bt, int ldb,
    unsigned short* __restrict__ Cbf, float* __restrict__ Cacc, int ldc,
    int K, const float* __restrict__ bias, int act){
  __shared__ unsigned short Asm[128*32];
  __shared__ unsigned short Bsm[128*32];
  int tid = threadIdx.x;
  int lane = tid & 63, wid = tid >> 6;
  int wrow = (wid>>1)*64, wcol = (wid&1)*64;
  int m0 = blockIdx.x*128, n0 = blockIdx.y*128;
  f4v acc[4][4];
#pragma unroll
  for(int mi=0;mi<4;mi++)
#pragma unroll
    for(int ni=0;ni<4;ni++) acc[mi][ni] = (f4v){0.f,0.f,0.f,0.f};
  int q = lane>>4, l16 = lane&15;
  int ra0 = tid>>2, ca0 = (tid&3)*8;
  int c1 = tid+256, ra1 = c1>>2, ca1 = (c1&3)*8;
  for(int k0=0;k0<K;k0+=32){
    glds16(A + (size_t)(m0+ra0)*lda + k0 + ca0, &Asm[tid*8]);
    glds16(A + (size_t)(m0+ra1)*lda + k0 + ca1, &Asm[c1*8]);
    glds16(Bt + (size_t)(n0+ra0)*ldb + k0 + ca0, &Bsm[tid*8]);
    glds16(Bt + (size_t)(n0+ra1)*ldb + k0 + ca1, &Bsm[c1*8]);
    __syncthreads();
    s8v af[4], bfr[4];
#pragma unroll
    for(int mi=0;mi<4;mi++) af[mi]  = *reinterpret_cast<const s8v*>(&Asm[(wrow+mi*16+l16)*32 + q*8]);
#pragma unroll
    for(int ni=0;ni<4;ni++) bfr[ni] = *reinterpret_cast<const s8v*>(&Bsm[(wcol+ni*16+l16)*32 + q*8]);
#pragma unroll
    for(int mi=0;mi<4;mi++)
#pragma unroll
      for(int ni=0;ni<4;ni++)
        acc[mi][ni] = __builtin_amdgcn_mfma_f32_16x16x32_bf16(af[mi], bfr[ni], acc[mi][ni], 0, 0, 0);
    __syncthreads();
  }
#pragma unroll
  for(int mi=0;mi<4;mi++)
#pragma unroll
    for(int ni=0;ni<4;ni++){
      int ccol = n0 + wcol + ni*16 + l16;
      float bv = bias ? bias[ccol] : 0.f;
#pragma unroll
      for(int r=0;r<4;r++){
        int crow = m0 + wrow + mi*16 + q*4 + r;
        float v = acc[mi][ni][r] + bv;
        if(act==1){
          float x = v;
          float z = 0.7978845608028654f*(x + 0.044715f*x*x*x);
          float t = 1.f - 2.f/(__expf(2.f*z) + 1.f);   // tanh(z), overflow-safe
          v = 0.5f*x*(1.f + t);
        }
        if(Cacc) Cacc[(size_t)crow*ldc + ccol] += v;
        else     Cbf[(size_t)crow*ldc + ccol] = f2bfu(v);
      }
    }
}

// ---------------- Orchestration ----------------
extern "C" void kernel_launch(void* const* d_in, const int* in_sizes, int n_in,
                              void* d_out, int out_size, void* d_ws, size_t ws_size,
                              hipStream_t stream) {
  const float* nodes    = (const float*)d_in[0];
  const int*   senders  = (const int*)d_in[1];
  const int*   receivers= (const int*)d_in[2];
  const float* alibi    = (const float*)d_in[3];
  const float* lnq_s    = (const float*)d_in[4];
  const float* lnq_o    = (const float*)d_in[5];
  const float* Wq       = (const float*)d_in[6];
  const float* bq       = (const float*)d_in[7];
  const float* Wk       = (const float*)d_in[8];
  const float* bk       = (const float*)d_in[9];
  const float* Wv       = (const float*)d_in[10];
  const float* bv       = (const float*)d_in[11];
  const float* lnm_s    = (const float*)d_in[12];
  const float* lnm_o    = (const float*)d_in[13];
  const float* W1       = (const float*)d_in[14];
  const float* b1       = (const float*)d_in[15];
  const float* W2       = (const float*)d_in[16];
  const float* b2       = (const float*)d_in[17];
  const float* lno_s    = (const float*)d_in[18];
  const float* lno_o    = (const float*)d_in[19];

  char* ws = (char*)d_ws;
  // layout (~137.7 MiB; 157 MiB proven safe):
  size_t o_nnorm = 0;                         // bf16 ROWS*256 = 33.5 MB ; H1c (16384x1024 bf16) overlay later
  size_t o_P2    = 33554432;                  // bf16 ROWS*320 = 41.9 MB ; Xm (bf16 33.5 MB) overlay later
  size_t o_attn  = 75497472;                  // fp32 ROWS*256 = 67.1 MB (gets D2 accumulated)
  size_t o_w1t   = 142606336;                 // 1024x256 bf16 = 524288
  size_t o_w2t   = 143130624;                 // 256x1024 bf16 = 524288
  size_t o_wall  = 143654912;                 // 4*320*256 bf16 = 655360
  size_t o_ball  = 144310272;                 // 4*320 fp32 = 5120
  size_t o_csr   = 144315392;
  size_t o_deg   = o_csr;
  size_t o_offs  = o_csr + 8192;
  size_t o_cur   = o_csr + 16640;
  size_t o_elist = o_csr + 24832;             // ends ~144.4 MB

  unsigned short* nnorm = (unsigned short*)(ws + o_nnorm);
  unsigned short* P2    = (unsigned short*)(ws + o_P2);
  float* attn = (float*)(ws + o_attn);
  unsigned short* w1t   = (unsigned short*)(ws + o_w1t);
  unsigned short* w2t   = (unsigned short*)(ws + o_w2t);
  unsigned short* WTall = (unsigned short*)(ws + o_wall);
  float* biasall = (float*)(ws + o_ball);
  int* deg    = (int*)(ws + o_deg);
  int* offs   = (int*)(ws + o_offs);
  int* cursor = (int*)(ws + o_cur);
  int* elist  = (int*)(ws + o_elist);
  unsigned short* H1c = (unsigned short*)(ws + o_nnorm);  // overlay (nnorm dead after last projg)
  unsigned short* Xm  = (unsigned short*)(ws + o_P2);     // overlay (P2 dead after attention)

  // CSR build
  k_zero_i32<<<8, 256, 0, stream>>>(deg, NN);
  k_hist<<<EE/256, 256, 0, stream>>>(receivers, deg);
  k_scan<<<1, 256, 0, stream>>>(deg, offs, cursor);
  k_scatter<<<EE/256, 256, 0, stream>>>(receivers, cursor, elist);

  // LN(nodes) -> nnorm (bf16)
  k_ln_f2b<<<ROWS/4, 256, 0, stream>>>(nodes, lnq_s, lnq_o, nnorm);

  // weights: W1/W2 transposed (fp32->bf16); fused projection weights
  k_transpose<<<dim3(32,8), 256, 0, stream>>>(W1, w1t, 256, 1024);
  k_transpose<<<dim3(8,32), 256, 0, stream>>>(W2, w2t, 1024, 256);
  k_buildw<<<4*320, 256, 0, stream>>>(Wq, Wk, Wv, bq, bk, bv, WTall, biasall);

  // attention: 4 passes of 2 heads
  for(int p=0;p<HH/HS;p++){
    k_projg<<<dim3(ROWS/128, 5), 256, 0, stream>>>(nnorm, WTall + (size_t)p*320*256,
                                                   biasall + p*320, P2);
    k_attn<<<NN*HS/4, 256, 0, stream>>>(P2, alibi, offs, elist, senders, attn, p*HS);
  }

  // FFN: Xm = LN(attn); 4 row-chunks of 16384: H1c = gelu(Xm@W1+b1); attn += H1c@W2+b2
  k_ln_f2b<<<ROWS/4, 256, 0, stream>>>(attn, lnm_s, lnm_o, Xm);
  for(int cch=0; cch<4; cch++){
    const unsigned short* Xc = Xm + (size_t)cch*16384*256;
    k_gemmL<<<dim3(128, 8), 256, 0, stream>>>(Xc, 256, w1t, 256,
                                              H1c, nullptr, 1024, 256, b1, 1);
    k_gemmL<<<dim3(128, 2), 256, 0, stream>>>(H1c, 1024, w2t, 1024,
                                              nullptr, attn + (size_t)cch*16384*256, 256,
                                              1024, b2, 0);
  }

  // out = LN(nodes + attn)
  k_final<<<ROWS/4, 256, 0, stream>>>(nodes, attn, lno_s, lno_o, (float*)d_out);
}